// Round 11
// baseline (363.317 us; speedup 1.0000x reference)
//
#include <hip/hip_runtime.h>
#include <hip/hip_bf16.h>
#include <math.h>

#define N_NODES 100000
#define N_EDGES 3200000
#define IN_FEATS 256
#define N_UNITS 32
#define OUT_FEATS 40

#define NPB 64                       // nodes per fine bucket
#define BSHIFT 6                     // dst >> 6 = fine bucket
#define NB 1563                      // ceil(100000/64) fine buckets
#define CAP 4096                     // max edges per fine bucket (avg 2048)

#define NC 49                        // coarse buckets (2048 nodes each)
#define CSHIFT 11                    // dst >> 11 = coarse bucket
#define CHUNK 8192                   // edges per bin block
#define NBLK ((N_EDGES + CHUNK - 1) / CHUNK)   // 391
#define WIN 128                      // fine-bucket window in pass B

// gemm split: half the nodes ride with binA, half with binB
#define GHALF 391                    // gemm blocks per half (391*128 = 50048 nodes)
#define NSPLIT (GHALF * 128)         // 50048

// outdeg hist riders (R10 structure kept): 4 slices x 96 stripes, 32KB each,
// ride in binAgemm; SWAR reduce rides in binBgemm -> inv_out before gather1.
#define ODS 32768
#define ODW 8192
#define OD_NSL 4
#define OD_STR 96
#define HIST_RIDERS (OD_NSL * OD_STR)          // 384
#define RED_RIDERS ((N_NODES / 4 + 511) / 512) // 49

// ================= K0: coarse (49-bin) dst histogram — the ONLY front kernel =================
// Fine-bucket counting moved INTO binA (it already reads every edge); bases are
// recomputed in-block from ccount+bucket_count prefixes. count+scan kernels deleted.
__global__ void __launch_bounds__(256) ccount_kernel(const int* __restrict__ dst,
                                                     int* __restrict__ ccount) {
    __shared__ int lh[NC];
    if (threadIdx.x < NC) lh[threadIdx.x] = 0;
    __syncthreads();
    const int4* d4 = (const int4*)dst;
    const int total4 = N_EDGES / 4;
    for (int i = blockIdx.x * 256 + threadIdx.x; i < total4; i += gridDim.x * 256) {
        int4 v = d4[i];
        atomicAdd(&lh[v.x >> CSHIFT], 1);
        atomicAdd(&lh[v.y >> CSHIFT], 1);
        atomicAdd(&lh[v.z >> CSHIFT], 1);
        atomicAdd(&lh[v.w >> CSHIFT], 1);
    }
    __syncthreads();
    if (threadIdx.x < NC && lh[threadIdx.x]) atomicAdd(&ccount[threadIdx.x], lh[threadIdx.x]);
}

// ---- shared gemm body (writes UNNORMALIZED h) ----
__device__ __forceinline__ void gemm_body(char* smem, int tid, int gblk,
                                          const float* __restrict__ x,
                                          const float* __restrict__ W1,
                                          float* __restrict__ h, int nbase) {
    float* Ws = (float*)smem;               // 32 KB
    for (int idx = tid; idx < IN_FEATS * N_UNITS / 4; idx += 512)
        ((float4*)Ws)[idx] = ((const float4*)W1)[idx];
    __syncthreads();
    unsigned n = (unsigned)(nbase + gblk * 128) + (tid >> 2);
    if (n >= (unsigned)N_NODES) return;
    unsigned j0 = (tid & 3) * 8;
    float acc[8] = {0, 0, 0, 0, 0, 0, 0, 0};
    const float4* xr = (const float4*)(x + (size_t)n * IN_FEATS);
    #pragma unroll 4
    for (int k4 = 0; k4 < IN_FEATS / 4; ++k4) {
        float4 xv = xr[k4];
        const float* wk = Ws + (k4 * 4) * N_UNITS + j0;
        #pragma unroll
        for (int jj = 0; jj < 8; ++jj) acc[jj] = fmaf(xv.x, wk[jj], acc[jj]);
        #pragma unroll
        for (int jj = 0; jj < 8; ++jj) acc[jj] = fmaf(xv.y, wk[N_UNITS + jj], acc[jj]);
        #pragma unroll
        for (int jj = 0; jj < 8; ++jj) acc[jj] = fmaf(xv.z, wk[2 * N_UNITS + jj], acc[jj]);
        #pragma unroll
        for (int jj = 0; jj < 8; ++jj) acc[jj] = fmaf(xv.w, wk[3 * N_UNITS + jj], acc[jj]);
    }
    float* hr = h + (size_t)n * N_UNITS + j0;
    #pragma unroll
    for (int jj = 0; jj < 8; ++jj) hr[jj] = acc[jj];
}

// ================= K1: gemm(lo) + binA (coarse bin + FINE COUNTING) + hist riders =================
#define BA_SORT 0
#define BA_HIST (CHUNK * 4)                       // NC ints
#define BA_LST  (BA_HIST + NC * 4)
#define BA_CUR  (BA_LST + NC * 4)
#define BA_GRES (BA_CUR + NC * 4)
#define BA_CB   (BA_GRES + NC * 4)                // NC+1 ints
#define BA_LHF  (BA_CB + (NC + 1) * 4)            // NB ints
#define BA_SMEM (BA_LHF + ((NB + 3) & ~3) * 4)    // ~40 KB -> 4 blocks/CU (unchanged)

__global__ void __launch_bounds__(512) binAgemm_kernel(const int* __restrict__ src,
                                                       const int* __restrict__ dst,
                                                       const int* __restrict__ ccount,
                                                       int* __restrict__ bucket_count,
                                                       int* __restrict__ gcursorA,
                                                       unsigned* __restrict__ pairsA,
                                                       const float* __restrict__ x,
                                                       const float* __restrict__ W1,
                                                       float* __restrict__ h,
                                                       unsigned* __restrict__ partials) {
    __shared__ __align__(16) char smem[BA_SMEM];
    int tid = threadIdx.x;
    if (blockIdx.x < GHALF) {
        gemm_body(smem, tid, blockIdx.x, x, W1, h, 0);
        return;
    }
    if (blockIdx.x >= GHALF + NBLK) {
        // ---- hist rider: 32KB byte-counter slice of outdeg ----
        unsigned* lh = (unsigned*)smem;
        int r = blockIdx.x - (GHALF + NBLK);
        int slice = r / OD_STR;
        int stripe = r % OD_STR;
        for (int i = tid; i < ODW; i += 512) lh[i] = 0;
        __syncthreads();
        int lo = slice * ODS;
        const int4* s4 = (const int4*)src;
        const int total4 = N_EDGES / 4;
        for (int i = stripe * 512 + tid; i < total4; i += OD_STR * 512) {
            int4 v = s4[i];
            unsigned a = (unsigned)(v.x - lo); if (a < ODS) atomicAdd(&lh[a >> 2], 1u << ((a & 3) * 8));
            unsigned b = (unsigned)(v.y - lo); if (b < ODS) atomicAdd(&lh[b >> 2], 1u << ((b & 3) * 8));
            unsigned c = (unsigned)(v.z - lo); if (c < ODS) atomicAdd(&lh[c >> 2], 1u << ((c & 3) * 8));
            unsigned d = (unsigned)(v.w - lo); if (d < ODS) atomicAdd(&lh[d >> 2], 1u << ((d & 3) * 8));
        }
        __syncthreads();
        int4* dstp = (int4*)(partials + (size_t)r * ODW);
        const int4* lh4 = (const int4*)lh;
        for (int i = tid; i < ODW / 4; i += 512) dstp[i] = lh4[i];
        return;
    }
    // ---- binA ----
    unsigned* sortedA = (unsigned*)(smem + BA_SORT);
    int* hist   = (int*)(smem + BA_HIST);
    int* lstart = (int*)(smem + BA_LST);
    int* cur    = (int*)(smem + BA_CUR);
    int* gres   = (int*)(smem + BA_GRES);
    int* cbaseS = (int*)(smem + BA_CB);
    int* lhf    = (int*)(smem + BA_LHF);
    int e0 = (blockIdx.x - GHALF) * CHUNK;
    int cnt = min(CHUNK, N_EDGES - e0);
    unsigned es[16], ed[16];
    #pragma unroll
    for (int r = 0; r < 16; ++r) {
        int idx = tid + 512 * r;
        if (idx < cnt) { es[r] = src[e0 + idx]; ed[r] = dst[e0 + idx]; }
    }
    if (tid < NC) hist[tid] = 0;
    for (int i = tid; i < NB; i += 512) lhf[i] = 0;
    if (tid < 64) {           // coarse bases: exclusive prefix of ccount
        int v = (tid < NC) ? ccount[tid] : 0;
        int inc = v;
        #pragma unroll
        for (int off = 1; off < 64; off <<= 1) {
            int u = __shfl_up(inc, off, 64);
            if (tid >= off) inc += u;
        }
        if (tid < NC) cbaseS[tid] = inc - v;
        if (tid == NC) cbaseS[NC] = N_EDGES;
    }
    __syncthreads();
    #pragma unroll
    for (int r = 0; r < 16; ++r) {
        int idx = tid + 512 * r;
        if (idx < cnt) {
            atomicAdd(&hist[ed[r] >> CSHIFT], 1);
            atomicAdd(&lhf[ed[r] >> BSHIFT], 1);   // fine counting (was count_kernel)
        }
    }
    __syncthreads();
    if (tid < 64) {
        int v = (tid < NC) ? hist[tid] : 0;
        int inc = v;
        #pragma unroll
        for (int off = 1; off < 64; off <<= 1) {
            int u = __shfl_up(inc, off, 64);
            if ((tid & 63) >= off) inc += u;
        }
        if (tid < NC) {
            int ls = inc - v;
            lstart[tid] = ls;
            cur[tid] = ls;
            gres[tid] = cbaseS[tid] + atomicAdd(&gcursorA[tid], v) - ls;
        }
    }
    __syncthreads();
    #pragma unroll
    for (int r = 0; r < 16; ++r) {
        int idx = tid + 512 * r;
        if (idx < cnt) {
            int c = ed[r] >> CSHIFT;
            int pos = atomicAdd(&cur[c], 1);
            sortedA[pos] = es[r] | ((ed[r] & ((1u << CSHIFT) - 1)) << 17);
        }
    }
    __syncthreads();
    for (int i = tid; i < cnt; i += 512) {
        int lo = 0, hi = NC - 1;
        while (lo < hi) { int mid = (lo + hi + 1) >> 1; if (lstart[mid] <= i) lo = mid; else hi = mid - 1; }
        pairsA[gres[lo] + i] = sortedA[i];
    }
    for (int i = tid; i < NB; i += 512)
        if (lhf[i]) atomicAdd(&bucket_count[i], lhf[i]);
}

// ================= K2: gemm(hi) + binB (in-block fine bases) + reduce riders =================
#define BB_SORT 0
#define BB_HIST (CHUNK * 4)
#define BB_LST  (BB_HIST + WIN * 4)
#define BB_CUR  (BB_LST + WIN * 4)
#define BB_GRES (BB_CUR + WIN * 4)
#define BB_CB   (BB_GRES + WIN * 4)
#define BB_SMEM (BB_CB + (NC + 2) * 4)

__global__ void __launch_bounds__(512) binBgemm_kernel(const unsigned* __restrict__ pairsA,
                                                       const int* __restrict__ ccount,
                                                       const int* __restrict__ bucket_count,
                                                       int* __restrict__ gcur_rel,
                                                       unsigned* __restrict__ pairs,
                                                       const float* __restrict__ x,
                                                       const float* __restrict__ W1,
                                                       float* __restrict__ h,
                                                       const unsigned* __restrict__ partials,
                                                       float* __restrict__ inv_out) {
    __shared__ __align__(16) char smem[BB_SMEM];
    int tid = threadIdx.x;
    if (blockIdx.x < GHALF) {
        gemm_body(smem, tid, blockIdx.x, x, W1, h, NSPLIT);
        return;
    }
    if (blockIdx.x >= GHALF + NBLK) {
        // ---- reduce rider: partials -> inv_out ----
        int w = (blockIdx.x - (GHALF + NBLK)) * 512 + tid;
        if (w >= N_NODES / 4) return;
        int slice = w >> 13;
        int wloc = w & (ODW - 1);
        const unsigned* p = partials + ((size_t)slice * OD_STR) * ODW + wloc;
        unsigned s = 0;
        #pragma unroll 8
        for (int j = 0; j < OD_STR; ++j) s += p[(size_t)j * ODW];
        float4 r;
        r.x = rsqrtf(fmaxf((float)(s & 0xFF), 1.0f));
        r.y = rsqrtf(fmaxf((float)((s >> 8) & 0xFF), 1.0f));
        r.z = rsqrtf(fmaxf((float)((s >> 16) & 0xFF), 1.0f));
        r.w = rsqrtf(fmaxf((float)(s >> 24), 1.0f));
        *(float4*)(inv_out + 4 * w) = r;
        return;
    }
    unsigned* sortedB = (unsigned*)(smem + BB_SORT);
    int* hist   = (int*)(smem + BB_HIST);
    int* lstart = (int*)(smem + BB_LST);
    int* cur    = (int*)(smem + BB_CUR);
    int* gres   = (int*)(smem + BB_GRES);
    int* gA     = (int*)(smem + BB_CB);      // coarse bases, NC+1
    if (tid < 64) {
        int v = (tid < NC) ? ccount[tid] : 0;
        int inc = v;
        #pragma unroll
        for (int off = 1; off < 64; off <<= 1) {
            int u = __shfl_up(inc, off, 64);
            if (tid >= off) inc += u;
        }
        if (tid < NC) gA[tid] = inc - v;
        if (tid == NC) gA[NC] = N_EDGES;
    }
    if (tid >= 64 && tid < 64 + WIN) hist[tid - 64] = 0;
    int e0 = (blockIdx.x - GHALF) * CHUNK;
    int cnt = min(CHUNK, N_EDGES - e0);
    __syncthreads();
    int c0 = 0;
    { int lo = 0, hi = NC - 1;
      while (lo < hi) { int mid = (lo + hi + 1) >> 1; if (gA[mid] <= e0) lo = mid; else hi = mid - 1; }
      c0 = lo; }
    int w0 = c0 * 32;
    unsigned pv[16]; short fw[16];
    int c = c0;
    #pragma unroll
    for (int r = 0; r < 16; ++r) {
        int idx = tid + 512 * r;
        if (idx < cnt) {
            int pos = e0 + idx;
            while (pos >= gA[c + 1]) ++c;
            unsigned p = pairsA[pos];
            unsigned srcid = p & 0x1FFFF;
            unsigned dl11 = (p >> 17) & 0x7FF;
            int wi = (c - c0) * 32 + (int)(dl11 >> 6);
            atomicAdd(&hist[wi], 1);
            pv[r] = srcid | ((dl11 & 63u) << 24);
            fw[r] = (short)wi;
        }
    }
    __syncthreads();
    if (tid < 64) {
        int v0 = hist[2 * tid], v1 = hist[2 * tid + 1];
        int s = v0 + v1;
        int inc = s;
        #pragma unroll
        for (int off = 1; off < 64; off <<= 1) {
            int u = __shfl_up(inc, off, 64);
            if ((tid & 63) >= off) inc += u;
        }
        int excl = inc - s;                  // block-local window prefix
        lstart[2 * tid] = excl;      cur[2 * tid] = excl;
        lstart[2 * tid + 1] = excl + v0; cur[2 * tid + 1] = excl + v0;
        int f0 = w0 + 2 * tid, f1 = f0 + 1;
        // global fine base = coarse base + 32-segmented prefix of bucket_count
        int bc0 = (f0 < NB) ? bucket_count[f0] : 0;
        int bc1 = (f1 < NB) ? bucket_count[f1] : 0;
        int ps = bc0 + bc1;
        int pinc = ps;
        #pragma unroll
        for (int off = 1; off < 16; off <<= 1) {
            int u = __shfl_up(pinc, off, 64);
            if ((tid & 15) >= off) pinc += u;
        }
        int pexcl = pinc - ps;               // prefix within 32-bucket region
        int creg = (w0 >> 5) + (tid >> 4);
        int gb0 = gA[creg < NC ? creg : NC] + pexcl;
        gres[2 * tid]     = (f0 < NB) ? (gb0 + atomicAdd(&gcur_rel[f0], v0) - excl) : 0;
        gres[2 * tid + 1] = (f1 < NB) ? (gb0 + bc0 + atomicAdd(&gcur_rel[f1], v1) - (excl + v0)) : 0;
    }
    __syncthreads();
    #pragma unroll
    for (int r = 0; r < 16; ++r) {
        int idx = tid + 512 * r;
        if (idx < cnt) {
            int pos = atomicAdd(&cur[fw[r]], 1);
            sortedB[pos] = pv[r];
        }
    }
    __syncthreads();
    for (int i = tid; i < cnt; i += 512) {
        int lo = 0, hi = WIN - 1;
        while (lo < hi) { int mid = (lo + hi + 1) >> 1; if (lstart[mid] <= i) lo = mid; else hi = mid - 1; }
        pairs[gres[lo] + i] = sortedB[i];
    }
}

// ================= K3/K4: bucketed gather (bases recomputed in-block) =================
template <bool LAYER1>
__global__ void __launch_bounds__(256) gather_kernel(
        const float* __restrict__ in, const unsigned* __restrict__ pairs,
        const int* __restrict__ ccount, const int* __restrict__ bucket_count,
        const float* __restrict__ inv_out,
        const float* __restrict__ b1, float* __restrict__ outbuf,
        float* __restrict__ inv_in) {
    __shared__ int sorted[CAP];
    __shared__ int cnt[NPB];
    __shared__ int start[NPB + 1];
    __shared__ int cur[NPB];
    __shared__ float b1s[N_UNITS];
    __shared__ int ebeg_s, ecnt_s;
    int tid = threadIdx.x;
    int b = blockIdx.x;
    if (tid < NPB) cnt[tid] = 0;
    if (LAYER1 && tid < N_UNITS) b1s[tid] = b1[tid];
    if (tid < 64) {
        // ebeg = prefix(ccount)[b>>5] + prefix32(bucket_count)[b]
        int reg = b >> 5;
        int base32 = b & ~31;
        int val = 0;
        if (tid < reg) val = ccount[tid];                       // reg <= 48 < 64
        if (tid < (b & 31)) {
            int fb = base32 + tid;
            if (fb < NB) val += bucket_count[fb];
        }
        #pragma unroll
        for (int st = 1; st < 64; st <<= 1) val += __shfl_xor(val, st, 64);
        if (tid == 0) { ebeg_s = val; ecnt_s = min(bucket_count[b], CAP); }
    }
    __syncthreads();
    int ebeg = ebeg_s;
    int ecnt = ecnt_s;

    unsigned stash[16];
    #pragma unroll
    for (int r = 0; r < 16; ++r) {
        int idx = tid + 256 * r;
        if (idx < ecnt) {
            unsigned p = pairs[ebeg + idx];
            stash[r] = p;
            atomicAdd(&cnt[p >> 24], 1);
        }
    }
    __syncthreads();

    if (tid < 64) {
        int v = cnt[tid];
        int inc = v;
        #pragma unroll
        for (int off = 1; off < 64; off <<= 1) {
            int u = __shfl_up(inc, off, 64);
            if (tid >= off) inc += u;
        }
        start[tid + 1] = inc;
        cur[tid] = inc - v;
        if (tid == 0) start[0] = 0;
    }
    __syncthreads();

    #pragma unroll
    for (int r = 0; r < 16; ++r) {
        int idx = tid + 256 * r;
        if (idx < ecnt) {
            unsigned p = stash[r];
            int pos = atomicAdd(&cur[p >> 24], 1);
            sorted[pos] = (int)(p & 0xFFFFFF);
        }
    }
    __syncthreads();

    int w = tid >> 6;
    int lane = tid & 63;
    int q = lane & 7;
    int eo = lane >> 3;
    int nd0 = b * NPB;
    #pragma unroll 1
    for (int p = 0; p < 16; ++p) {
        int nd = w * 16 + p;
        int n = nd0 + nd;
        int beg = start[nd];
        int end = start[nd + 1];
        float ax0 = 0.f, ay0 = 0.f, az0 = 0.f, aw0 = 0.f;
        float ax1 = 0.f, ay1 = 0.f, az1 = 0.f, aw1 = 0.f;
        int e = beg + eo;
        for (; e + 8 < end; e += 16) {
            int s0 = sorted[e];
            int s1 = sorted[e + 8];
            float4 v0 = *(const float4*)(in + (size_t)s0 * N_UNITS + q * 4);
            float4 v1 = *(const float4*)(in + (size_t)s1 * N_UNITS + q * 4);
            if (LAYER1) {
                float io0 = inv_out[s0];
                float io1 = inv_out[s1];
                ax0 = fmaf(v0.x, io0, ax0); ay0 = fmaf(v0.y, io0, ay0);
                az0 = fmaf(v0.z, io0, az0); aw0 = fmaf(v0.w, io0, aw0);
                ax1 = fmaf(v1.x, io1, ax1); ay1 = fmaf(v1.y, io1, ay1);
                az1 = fmaf(v1.z, io1, az1); aw1 = fmaf(v1.w, io1, aw1);
            } else {
                ax0 += v0.x; ay0 += v0.y; az0 += v0.z; aw0 += v0.w;
                ax1 += v1.x; ay1 += v1.y; az1 += v1.z; aw1 += v1.w;
            }
        }
        if (e < end) {
            int s0 = sorted[e];
            float4 v = *(const float4*)(in + (size_t)s0 * N_UNITS + q * 4);
            if (LAYER1) {
                float io0 = inv_out[s0];
                ax0 = fmaf(v.x, io0, ax0); ay0 = fmaf(v.y, io0, ay0);
                az0 = fmaf(v.z, io0, az0); aw0 = fmaf(v.w, io0, aw0);
            } else {
                ax0 += v.x; ay0 += v.y; az0 += v.z; aw0 += v.w;
            }
        }
        e += 8;
        if (e < end) {
            int s1 = sorted[e];
            float4 v = *(const float4*)(in + (size_t)s1 * N_UNITS + q * 4);
            if (LAYER1) {
                float io1 = inv_out[s1];
                ax1 = fmaf(v.x, io1, ax1); ay1 = fmaf(v.y, io1, ay1);
                az1 = fmaf(v.z, io1, az1); aw1 = fmaf(v.w, io1, aw1);
            } else {
                ax1 += v.x; ay1 += v.y; az1 += v.z; aw1 += v.w;
            }
        }
        float sx = ax0 + ax1, sy = ay0 + ay1, sz = az0 + az1, sw = aw0 + aw1;
        #pragma unroll
        for (int st = 8; st < 64; st <<= 1) {
            sx += __shfl_xor(sx, st, 64);
            sy += __shfl_xor(sy, st, 64);
            sz += __shfl_xor(sz, st, 64);
            sw += __shfl_xor(sw, st, 64);
        }
        if (eo == 0 && n < N_NODES) {
            if (LAYER1) {
                float ii = rsqrtf(fmaxf((float)(end - beg), 1.0f));
                float io = inv_out[n];
                float4 r;
                r.x = fmaxf(fmaf(sx, ii, b1s[q * 4 + 0]), 0.0f) * io;
                r.y = fmaxf(fmaf(sy, ii, b1s[q * 4 + 1]), 0.0f) * io;
                r.z = fmaxf(fmaf(sz, ii, b1s[q * 4 + 2]), 0.0f) * io;
                r.w = fmaxf(fmaf(sw, ii, b1s[q * 4 + 3]), 0.0f) * io;
                *(float4*)(outbuf + (size_t)n * N_UNITS + q * 4) = r;
                if (q == 0) inv_in[n] = ii;
            } else {
                *(float4*)(outbuf + (size_t)n * N_UNITS + q * 4) =
                    make_float4(sx, sy, sz, sw);
            }
        }
    }
}

// ================= K5: v = (agg2 @ W2)*inv_in + b2 ; out = log_softmax(v) =================
__global__ void __launch_bounds__(256) finalize_kernel(
        const float* __restrict__ agg2, const float* __restrict__ inv_in,
        const float* __restrict__ W2, const float* __restrict__ b2,
        float* __restrict__ out, int N) {
    __shared__ float W2s[N_UNITS * OUT_FEATS];
    __shared__ float b2s[OUT_FEATS];
    for (int i = threadIdx.x; i < N_UNITS * OUT_FEATS; i += 256) W2s[i] = W2[i];
    if (threadIdx.x < OUT_FEATS) b2s[threadIdx.x] = b2[threadIdx.x];
    __syncthreads();
    int n = blockIdx.x * 256 + threadIdx.x;
    if (n >= N) return;
    float a[N_UNITS];
    const float4* ar = (const float4*)(agg2 + (size_t)n * N_UNITS);
    #pragma unroll
    for (int qq = 0; qq < N_UNITS / 4; ++qq) {
        float4 v = ar[qq];
        a[qq * 4 + 0] = v.x; a[qq * 4 + 1] = v.y; a[qq * 4 + 2] = v.z; a[qq * 4 + 3] = v.w;
    }
    float ii = inv_in[n];
    float s[OUT_FEATS];
    #pragma unroll
    for (int o = 0; o < OUT_FEATS; ++o) s[o] = 0.0f;
    #pragma unroll
    for (int k = 0; k < N_UNITS; ++k) {
        float ak = a[k];
        #pragma unroll
        for (int o = 0; o < OUT_FEATS; ++o) s[o] = fmaf(ak, W2s[k * OUT_FEATS + o], s[o]);
    }
    float mx = -INFINITY;
    #pragma unroll
    for (int o = 0; o < OUT_FEATS; ++o) {
        s[o] = fmaf(s[o], ii, b2s[o]);
        mx = fmaxf(mx, s[o]);
    }
    float sum = 0.0f;
    #pragma unroll
    for (int o = 0; o < OUT_FEATS; ++o) sum += __expf(s[o] - mx);
    float lse = mx + __logf(sum);
    #pragma unroll
    for (int o = 0; o < OUT_FEATS; ++o) s[o] -= lse;
    float4* orow4 = (float4*)(out + (size_t)n * OUT_FEATS);
    #pragma unroll
    for (int qq = 0; qq < OUT_FEATS / 4; ++qq)
        orow4[qq] = make_float4(s[qq * 4], s[qq * 4 + 1], s[qq * 4 + 2], s[qq * 4 + 3]);
}

extern "C" void kernel_launch(void* const* d_in, const int* in_sizes, int n_in,
                              void* d_out, int out_size, void* d_ws, size_t ws_size,
                              hipStream_t stream) {
    const float* x   = (const float*)d_in[0];
    const float* W1  = (const float*)d_in[1];
    const float* b1  = (const float*)d_in[2];
    const float* W2  = (const float*)d_in[3];
    const float* b2  = (const float*)d_in[4];
    const int*   src = (const int*)d_in[5];
    const int*   dst = (const int*)d_in[6];
    float* out = (float*)d_out;

    // -------- workspace layout --------
    char* base = (char*)d_ws;
    float*    inv_out      = (float*)(base);                // [N]    400000 B (riders write all)
    int*      ccount       = (int*)(base + 400000L);        // [NC]
    int*      bucket_count = (int*)(base + 400256L);        // [NB]
    int*      gcursorA     = (int*)(base + 406528L);        // [NC]   relative cursors
    int*      gcur_rel     = (int*)(base + 406784L);        // [NB]   relative cursors
    float*    inv_in       = (float*)(base + 424576L);      // [N]    400000 B
    unsigned* pairs        = (unsigned*)(base + 824576L);   // [E]    12.8 MB
    unsigned* pairsA       = (unsigned*)(base + 13624576L); // [E]    12.8 MB (own slot)
    float*    rprime       = (float*)(base + 26424576L);    // [N*32]
    float*    h            = (float*)(base + 39224576L);    // [N*32] — aliases agg2
    float*    agg2         = (float*)(base + 39224576L);
    unsigned* partials     = (unsigned*)rprime;             // 12.3 MB over rprime (dead before gather1)

    // zero ccount/bucket_count/cursors in one shot
    hipMemsetAsync(base + 400000L, 0, 13056L, stream);

    ccount_kernel<<<128, 256, 0, stream>>>(dst, ccount);

    binAgemm_kernel<<<GHALF + NBLK + HIST_RIDERS, 512, 0, stream>>>(
        src, dst, ccount, bucket_count, gcursorA, pairsA, x, W1, h, partials);
    binBgemm_kernel<<<GHALF + NBLK + RED_RIDERS, 512, 0, stream>>>(
        pairsA, ccount, bucket_count, gcur_rel, pairs, x, W1, h, partials, inv_out);

    gather_kernel<true><<<NB, 256, 0, stream>>>(h, pairs, ccount, bucket_count,
                                                inv_out, b1, rprime, inv_in);
    gather_kernel<false><<<NB, 256, 0, stream>>>(rprime, pairs, ccount, bucket_count,
                                                 inv_out, b1, agg2, inv_in);

    finalize_kernel<<<(N_NODES + 255) / 256, 256, 0, stream>>>(agg2, inv_in, W2, b2, out, N_NODES);
}